// Round 5
// baseline (281.081 us; speedup 1.0000x reference)
//
#include <hip/hip_runtime.h>
#include <math.h>

#define NBATCH 32
#define NL     4096
#define NC     8
#define NT     64
#define NTOT   (NBATCH * NL * NC)   // 1,048,576 delta elements

typedef float f32x4 __attribute__((ext_vector_type(4)));
typedef float f32x2 __attribute__((ext_vector_type(2)));

// ---------------------------------------------------------------------------
// Kernel 1: fp64 sum / sumsq of delta, vectorized float4.
// delta[b,l,c] = (l==0) ? 0 : in[b,l,c] - in[b,l-1,c], layout [B,L,C] (C=8).
// A float4 at element e (e%4==0) lies entirely within one l-row (8 floats),
// so l==0 for the whole vector iff (e mod L*C) < C. prev-row float4 is at
// vector index g-2 (8 floats back), 16B-aligned.
// Summation order differs from numpy's — R1/R3/R4 absmax==0.0 shows the spike
// decision margins tolerate ~1e-16 relative perturbation of mean/var.
// ---------------------------------------------------------------------------
__global__ __launch_bounds__(256) void reduce_kernel(const float* __restrict__ in,
                                                     double* __restrict__ part) {
    __shared__ double sm[256], sm2[256];
    const int tid = threadIdx.x;
    const f32x4* in4 = reinterpret_cast<const f32x4*>(in);
    double s = 0.0, s2 = 0.0;
    for (int g = blockIdx.x * 256 + tid; g < NTOT / 4; g += 256 * 256) {
        const int e = g * 4;
        if ((e & (NL * NC - 1)) >= NC) {
            const f32x4 cur = in4[g];
            const f32x4 prv = in4[g - 2];
            const double d0 = (double)cur.x - (double)prv.x;
            const double d1 = (double)cur.y - (double)prv.y;
            const double d2 = (double)cur.z - (double)prv.z;
            const double d3 = (double)cur.w - (double)prv.w;
            s  += d0 + d1 + d2 + d3;
            s2 += d0 * d0 + d1 * d1 + d2 * d2 + d3 * d3;
        }
    }
    sm[tid] = s; sm2[tid] = s2;
    __syncthreads();
    for (int off = 128; off > 0; off >>= 1) {
        if (tid < off) { sm[tid] += sm[tid + off]; sm2[tid] += sm2[tid + off]; }
        __syncthreads();
    }
    if (tid == 0) {
        part[2 * blockIdx.x]     = sm[0];
        part[2 * blockIdx.x + 1] = sm2[0];
    }
}

// ---------------------------------------------------------------------------
// Kernel 2: reduce partials -> mean/var -> per-t fp64 constants:
//   v' = 0.5*v + 0.5*(delta*A + Bc)*w[t] + 0.5*b[t]
//      = fma(v, 0.5, fma(delta, P[t], Q[t]))
//   P[t] = 0.5*A*w[t],  Q[t] = 0.5*(Bc*w[t] + b[t])
//   A = gamma*rsqrt(var+eps), Bc = beta - mean*A
// ---------------------------------------------------------------------------
__global__ __launch_bounds__(256) void finalize_kernel(const double* __restrict__ part,
                                                       const float* __restrict__ gamma,
                                                       const float* __restrict__ beta,
                                                       const float* __restrict__ wv,
                                                       const float* __restrict__ bv,
                                                       double2* __restrict__ pq) {
    __shared__ double sm[256], sm2[256];
    __shared__ double sAB[2];
    const int tid = threadIdx.x;
    sm[tid]  = part[2 * tid];
    sm2[tid] = part[2 * tid + 1];
    __syncthreads();
    for (int off = 128; off > 0; off >>= 1) {
        if (tid < off) { sm[tid] += sm[tid + off]; sm2[tid] += sm2[tid + off]; }
        __syncthreads();
    }
    if (tid == 0) {
        const double mean = sm[0] / (double)NTOT;
        const double var  = sm2[0] / (double)NTOT - mean * mean;
        const double inv  = 1.0 / sqrt(var + 1e-5);
        const double A    = inv * (double)gamma[0];
        const double Bc   = (double)beta[0] - mean * A;
        sAB[0] = A;
        sAB[1] = Bc;
    }
    __syncthreads();
    if (tid < NT) {
        const double A  = sAB[0];
        const double Bc = sAB[1];
        const double w  = (double)wv[tid];
        const double b  = (double)bv[tid];
        double2 r;
        r.x = 0.5 * A * w;
        r.y = 0.5 * (Bc * w + b);
        pq[tid] = r;
    }
}

// ---------------------------------------------------------------------------
// Kernel 3: LIF over T=64 steps, fp64 state (bit-matches fp64 np ref on every
// binary spike decision; R1/R3/R4 absmax == 0.0).
// R5: no LDS — pq[t] is grid-uniform, read directly so the backend promotes
// it to s_load (constant cache, SGPRs); removes ds_read+lgkmcnt per t and the
// barrier, trims VGPRs. Nontemporal stores: 268 MB of never-re-read output
// should not thrash L2. 2048 blocks x 256 thr, 2 neurons/thread = 32 waves/CU.
// ---------------------------------------------------------------------------
__global__ __launch_bounds__(256) void lif_kernel(const float* __restrict__ in,
                                                  const double2* __restrict__ pq,
                                                  float* __restrict__ out) {
    const int blk   = blockIdx.x;      // 0..2047 = B(32) * C(8) * (L/512)(8)
    const int chunk = blk & 7;
    const int bc    = blk >> 3;
    const int c     = bc & 7;
    const int b     = bc >> 3;
    const int l     = chunk * 512 + threadIdx.x * 2;

    // 3 loads for 2 deltas: prv[1] == cur[0].
    const float* base = in + (b * NL + l) * NC + c;
    const float p0 = (l == 0) ? 0.0f : base[-NC];
    const float c0 = base[0];
    const float c1 = base[NC];

    const double dl0 = (l == 0) ? 0.0 : ((double)c0 - (double)p0);
    const double dl1 = (double)c1 - (double)c0;

    double v0 = 0.0, v1 = 0.0;
    f32x2* obase = reinterpret_cast<f32x2*>(out + ((b * NT) * NC + c) * NL + l);

#pragma unroll 8
    for (int t = 0; t < NT; t++) {
        const double2 PQ = pq[t];   // grid-uniform -> scalar load
        f32x2 o;
        double vv;
        bool s;

        vv = fma(v0, 0.5, fma(dl0, PQ.x, PQ.y));
        s = vv >= 1.0; o.x = s ? 1.0f : 0.0f; v0 = s ? 0.0 : vv;

        vv = fma(v1, 0.5, fma(dl1, PQ.x, PQ.y));
        s = vv >= 1.0; o.y = s ? 1.0f : 0.0f; v1 = s ? 0.0 : vv;

        __builtin_nontemporal_store(o, obase + t * (NC * NL / 2));
    }
}

extern "C" void kernel_launch(void* const* d_in, const int* in_sizes, int n_in,
                              void* d_out, int out_size, void* d_ws, size_t ws_size,
                              hipStream_t stream) {
    const float* inputs = (const float*)d_in[0];   // [B, L, C]
    const float* gamma  = (const float*)d_in[1];   // [1]
    const float* beta   = (const float*)d_in[2];   // [1]
    const float* enc_w  = (const float*)d_in[3];   // [T, 1]
    const float* enc_b  = (const float*)d_in[4];   // [T]
    float* out = (float*)d_out;                    // [B, T, C, L]

    double*  part = (double*)d_ws;                 // 512 doubles (256 blocks x 2)
    double2* pq   = (double2*)(part + 512);        // 64 double2 {P, Q}

    reduce_kernel  <<<256,  256, 0, stream>>>(inputs, part);
    finalize_kernel<<<1,    256, 0, stream>>>(part, gamma, beta, enc_w, enc_b, pq);
    lif_kernel     <<<2048, 256, 0, stream>>>(inputs, pq, out);
}

// Round 6
// 268.413 us; speedup vs baseline: 1.0472x; 1.0472x over previous
//
#include <hip/hip_runtime.h>
#include <math.h>

#define NBATCH 32
#define NL     4096
#define NC     8
#define NT     64
#define NTOT   (NBATCH * NL * NC)   // 1,048,576 delta elements

typedef float f32x4 __attribute__((ext_vector_type(4)));

// ---------------------------------------------------------------------------
// Kernel 1: fp64 sum / sumsq of delta, vectorized float4.
// delta[b,l,c] = (l==0) ? 0 : in[b,l,c] - in[b,l-1,c], layout [B,L,C] (C=8).
// A float4 at element e (e%4==0) lies entirely within one l-row (8 floats),
// so l==0 for the whole vector iff (e mod L*C) < C. prev-row float4 is at
// vector index g-2 (8 floats back), 16B-aligned.
// Summation order differs from numpy's — R1/R3/R4/R5 absmax==0.0 shows the
// spike decision margins tolerate ~1e-16 relative perturbation of mean/var.
// ---------------------------------------------------------------------------
__global__ __launch_bounds__(256) void reduce_kernel(const float* __restrict__ in,
                                                     double* __restrict__ part) {
    __shared__ double sm[256], sm2[256];
    const int tid = threadIdx.x;
    const f32x4* in4 = reinterpret_cast<const f32x4*>(in);
    double s = 0.0, s2 = 0.0;
    for (int g = blockIdx.x * 256 + tid; g < NTOT / 4; g += 256 * 256) {
        const int e = g * 4;
        if ((e & (NL * NC - 1)) >= NC) {
            const f32x4 cur = in4[g];
            const f32x4 prv = in4[g - 2];
            const double d0 = (double)cur.x - (double)prv.x;
            const double d1 = (double)cur.y - (double)prv.y;
            const double d2 = (double)cur.z - (double)prv.z;
            const double d3 = (double)cur.w - (double)prv.w;
            s  += d0 + d1 + d2 + d3;
            s2 += d0 * d0 + d1 * d1 + d2 * d2 + d3 * d3;
        }
    }
    sm[tid] = s; sm2[tid] = s2;
    __syncthreads();
    for (int off = 128; off > 0; off >>= 1) {
        if (tid < off) { sm[tid] += sm[tid + off]; sm2[tid] += sm2[tid + off]; }
        __syncthreads();
    }
    if (tid == 0) {
        part[2 * blockIdx.x]     = sm[0];
        part[2 * blockIdx.x + 1] = sm2[0];
    }
}

// ---------------------------------------------------------------------------
// Kernel 2: reduce partials -> mean/var -> per-t fp64 constants:
//   v' = 0.5*v + 0.5*(delta*A + Bc)*w[t] + 0.5*b[t]
//      = fma(v, 0.5, fma(delta, P[t], Q[t]))
//   P[t] = 0.5*A*w[t],  Q[t] = 0.5*(Bc*w[t] + b[t])
//   A = gamma*rsqrt(var+eps), Bc = beta - mean*A
// ---------------------------------------------------------------------------
__global__ __launch_bounds__(256) void finalize_kernel(const double* __restrict__ part,
                                                       const float* __restrict__ gamma,
                                                       const float* __restrict__ beta,
                                                       const float* __restrict__ wv,
                                                       const float* __restrict__ bv,
                                                       double2* __restrict__ pq) {
    __shared__ double sm[256], sm2[256];
    __shared__ double sAB[2];
    const int tid = threadIdx.x;
    sm[tid]  = part[2 * tid];
    sm2[tid] = part[2 * tid + 1];
    __syncthreads();
    for (int off = 128; off > 0; off >>= 1) {
        if (tid < off) { sm[tid] += sm[tid + off]; sm2[tid] += sm2[tid + off]; }
        __syncthreads();
    }
    if (tid == 0) {
        const double mean = sm[0] / (double)NTOT;
        const double var  = sm2[0] / (double)NTOT - mean * mean;
        const double inv  = 1.0 / sqrt(var + 1e-5);
        const double A    = inv * (double)gamma[0];
        const double Bc   = (double)beta[0] - mean * A;
        sAB[0] = A;
        sAB[1] = Bc;
    }
    __syncthreads();
    if (tid < NT) {
        const double A  = sAB[0];
        const double Bc = sAB[1];
        const double w  = (double)wv[tid];
        const double b  = (double)bv[tid];
        double2 r;
        r.x = 0.5 * A * w;
        r.y = 0.5 * (Bc * w + b);
        pq[tid] = r;
    }
}

// ---------------------------------------------------------------------------
// Kernel 3: LIF over T=64 steps, fp64 state (bit-matches fp64 np ref on every
// binary spike decision; absmax == 0.0 all rounds).
// R6 = exact R4 revert (best measured: 270.1 µs total):
//  - 2 neurons/thread, 2048 blocks x 256 thr = 32 waves/CU (occupancy max).
//  - LDS broadcast of pq (conflict-free wave-uniform ds_read).
//  - PLAIN float2 stores. Nontemporal regressed +11 µs in BOTH R3 and R5:
//    on gfx950 the nt flag hurts the L2->HBM write path for full-line
//    streaming stores. Do not reintroduce.
//  - unroll 8 (full unroll regressed in R3; VGPR pressure vs 8-deep pipeline).
// ---------------------------------------------------------------------------
__global__ __launch_bounds__(256) void lif_kernel(const float* __restrict__ in,
                                                  const double2* __restrict__ pq,
                                                  float* __restrict__ out) {
    __shared__ __align__(16) double2 spq[NT];
    const int tid = threadIdx.x;
    if (tid < NT) spq[tid] = pq[tid];
    __syncthreads();

    const int blk   = blockIdx.x;      // 0..2047 = B(32) * C(8) * (L/512)(8)
    const int chunk = blk & 7;
    const int bc    = blk >> 3;
    const int c     = bc & 7;
    const int b     = bc >> 3;
    const int l     = chunk * 512 + tid * 2;

    // 3 loads for 2 deltas: prv[1] == cur[0].
    const float* base = in + (b * NL + l) * NC + c;
    const float p0 = (l == 0) ? 0.0f : base[-NC];
    const float c0 = base[0];
    const float c1 = base[NC];

    const double dl0 = (l == 0) ? 0.0 : ((double)c0 - (double)p0);
    const double dl1 = (double)c1 - (double)c0;

    double v0 = 0.0, v1 = 0.0;
    float2* obase = reinterpret_cast<float2*>(out + ((b * NT) * NC + c) * NL + l);

#pragma unroll 8
    for (int t = 0; t < NT; t++) {
        const double2 PQ = spq[t];
        float2 o;
        double vv;
        bool s;

        vv = fma(v0, 0.5, fma(dl0, PQ.x, PQ.y));
        s = vv >= 1.0; o.x = s ? 1.0f : 0.0f; v0 = s ? 0.0 : vv;

        vv = fma(v1, 0.5, fma(dl1, PQ.x, PQ.y));
        s = vv >= 1.0; o.y = s ? 1.0f : 0.0f; v1 = s ? 0.0 : vv;

        obase[t * (NC * NL / 2)] = o;
    }
}

extern "C" void kernel_launch(void* const* d_in, const int* in_sizes, int n_in,
                              void* d_out, int out_size, void* d_ws, size_t ws_size,
                              hipStream_t stream) {
    const float* inputs = (const float*)d_in[0];   // [B, L, C]
    const float* gamma  = (const float*)d_in[1];   // [1]
    const float* beta   = (const float*)d_in[2];   // [1]
    const float* enc_w  = (const float*)d_in[3];   // [T, 1]
    const float* enc_b  = (const float*)d_in[4];   // [T]
    float* out = (float*)d_out;                    // [B, T, C, L]

    double*  part = (double*)d_ws;                 // 512 doubles (256 blocks x 2)
    double2* pq   = (double2*)(part + 512);        // 64 double2 {P, Q}

    reduce_kernel  <<<256,  256, 0, stream>>>(inputs, part);
    finalize_kernel<<<1,    256, 0, stream>>>(part, gamma, beta, enc_w, enc_b, pq);
    lif_kernel     <<<2048, 256, 0, stream>>>(inputs, pq, out);
}